// Round 8
// baseline (215.610 us; speedup 1.0000x reference)
//
#include <hip/hip_runtime.h>
#include <hip/hip_bf16.h>

// NPairLoss on MI355X (gfx950).
// loss = mean_i [ log( rowsum_i + e ) - pos_sim_i ] + 0.02*||examples||_F
// rowsum_i = sum_j exp(sim_ij), sim = (A/|A|)·(P/|P|)^T ; diag-replacement -> +e.
//
// R8 = R7 (fp8-e4m3, mfma_scale_f32_16x16x128_f8f6f4, identity scales 0x7F,
// verified correct) with the SPILL fixed: A-fragments loaded one-at-a-time in
// the unrolled mi loop (8 live arch regs instead of 32), bf[4] hoisted per
// slice. R7 counters showed WRITE 311MB/FETCH 175MB = scratch traffic from
// arch-register pressure (acc 128 + af 32 + bf 32 + addr > 128-reg split).

#define NR 8192
#define DD 512
#define E_CONST 2.71828182845904523536f

typedef __attribute__((ext_vector_type(4))) float f32x4_t;
typedef __attribute__((ext_vector_type(4))) int   i32x4_t;
typedef __attribute__((ext_vector_type(8))) int   i32x8_t;
typedef unsigned char uchar;
typedef unsigned int  uint;
#define AS1 __attribute__((address_space(1)))
#define AS3 __attribute__((address_space(3)))

// ---------------- prep: normalize rows -> fp8 e4m3, pos_sim, norm2, zero ----
__global__ __launch_bounds__(128) void prep_kernel(
    const float* __restrict__ ex,
    uchar* __restrict__ Ah, uchar* __restrict__ Ph,
    float* __restrict__ pos_sim, float* __restrict__ norm2,
    float* __restrict__ rowsum)
{
    const int i = blockIdx.x;
    const int t = threadIdx.x;            // 0..127, 4 floats each
    const float4 a = ((const float4*)(ex + (size_t)i * 1024))[t];
    const float4 p = ((const float4*)(ex + (size_t)i * 1024 + 512))[t];
    float sa  = a.x*a.x + a.y*a.y + a.z*a.z + a.w*a.w;
    float sp  = p.x*p.x + p.y*p.y + p.z*p.z + p.w*p.w;
    float sap = a.x*p.x + a.y*p.y + a.z*p.z + a.w*p.w;
    #pragma unroll
    for (int m = 1; m < 64; m <<= 1) {
        sa  += __shfl_xor(sa,  m, 64);
        sp  += __shfl_xor(sp,  m, 64);
        sap += __shfl_xor(sap, m, 64);
    }
    __shared__ float red[3][2];
    if ((t & 63) == 0) { red[0][t>>6] = sa; red[1][t>>6] = sp; red[2][t>>6] = sap; }
    __syncthreads();
    sa  = red[0][0] + red[0][1];
    sp  = red[1][0] + red[1][1];
    sap = red[2][0] + red[2][1];
    const float inva = rsqrtf(sa);
    const float invp = rsqrtf(sp);
    uint pa = 0, pp = 0;
    pa = __builtin_amdgcn_cvt_pk_fp8_f32(a.x * inva, a.y * inva, pa, false);
    pa = __builtin_amdgcn_cvt_pk_fp8_f32(a.z * inva, a.w * inva, pa, true);
    pp = __builtin_amdgcn_cvt_pk_fp8_f32(p.x * invp, p.y * invp, pp, false);
    pp = __builtin_amdgcn_cvt_pk_fp8_f32(p.z * invp, p.w * invp, pp, true);
    ((uint*)Ah)[i * 128 + t] = pa;
    ((uint*)Ph)[i * 128 + t] = pp;
    if (t == 0) {
        pos_sim[i] = sap * inva * invp;
        norm2[i]   = sa + sp;
        rowsum[i]  = 0.0f;
    }
}

// ---------------- GEMM 256^2 fp8, 4 slices of K=128, 2-phase dbuf -----------
__global__ __launch_bounds__(512, 2) void gemm_kernel(
    const uchar* __restrict__ Ah, const uchar* __restrict__ Ph,
    float* __restrict__ rowsum)
{
    // ls: 2 buffers x (A: 256x128B + B: 256x128B) = 2 x 64 KiB = 128 KiB
    __shared__ uchar ls[131072];
    const int t  = threadIdx.x;           // 0..511
    const int w  = t >> 6;                // wave 0..7
    const int l  = t & 63;
    const int wr = w >> 2, wc = w & 3;    // 2M x 4N wave grid
    const int ll = l & 15, lh = l >> 4;
    const int m0 = blockIdx.y * 256;
    const int n0 = blockIdx.x * 256;

    f32x4_t acc[8][4];
    #pragma unroll
    for (int i = 0; i < 8; i++)
        #pragma unroll
        for (int j = 0; j < 4; j++)
            acc[i][j] = (f32x4_t){0.f, 0.f, 0.f, 0.f};

    // staging: chunk = one matrix x one slice = 256 rows x 128 B = 32 KiB.
    // wave w, instr j: rows w*32+j*8..+8 -> 1 KiB LINEAR LDS (lane l at +l*16).
    // lane l -> row r = w*32+j*8+(l>>3), slot l&7; (r&7) == (l>>3).
    // Source fetches slot (l&7)^(r&7)  => LDS[r][s] = G[r][s^(r&7)] involution.
    auto stage = [&](const uchar* src, int s, int matOff, int rowBase) {
        const int buf = s & 1;
        #pragma unroll
        for (int j = 0; j < 4; ++j) {
            const int r  = w * 32 + j * 8 + (l >> 3);
            const int gs = (l & 7) ^ (r & 7);
            const uchar* g = src + (size_t)(rowBase + r) * DD + s * 128 + gs * 16;
            __builtin_amdgcn_global_load_lds(
                (const AS1 void*)g,
                (AS3 void*)(&ls[buf * 65536 + matOff + w * 4096 + j * 1024 + l * 16]),
                16, 0, 0);
        }
    };

    // fragment read: row R, lane wants global 16B-slots g=lh*2, lh*2+1 which
    // live at LDS slots g ^ (R&7), and (R&7) == (ll&7) (row bases 16-aligned).
    auto rdfrag = [&](int base, int R) -> i32x8_t {
        const int rb = base + R * 128;
        i32x4_t lo = *(const i32x4_t*)&ls[rb + (((lh * 2)    ) ^ (ll & 7)) * 16];
        i32x4_t hi = *(const i32x4_t*)&ls[rb + (((lh * 2) + 1) ^ (ll & 7)) * 16];
        return __builtin_shufflevector(lo, hi, 0, 1, 2, 3, 4, 5, 6, 7);
    };

    // prologue: stage slice 0, drain, barrier.
    stage(Ah, 0, 0,     m0);
    stage(Ph, 0, 32768, n0);
    __syncthreads();

    #pragma unroll
    for (int s = 0; s < 4; ++s) {
        // issue next slice's stages EARLY (latency hides under compute)
        if (s < 3) {
            stage(Ah, s + 1, 0,     m0);
            stage(Ph, s + 1, 32768, n0);
        }
        const int aB = (s & 1) * 65536;
        const int bB = aB + 32768;

        i32x8_t bf[4];
        #pragma unroll
        for (int ni = 0; ni < 4; ++ni)
            bf[ni] = rdfrag(bB, wc * 64 + ni * 16 + ll);

        // ONE A-fragment live at a time (spill fix): 8 arch regs vs 32.
        #pragma unroll
        for (int mi = 0; mi < 8; ++mi) {
            i32x8_t af = rdfrag(aB, wr * 128 + mi * 16 + ll);
            __builtin_amdgcn_s_setprio(1);
            #pragma unroll
            for (int ni = 0; ni < 4; ++ni)
                acc[mi][ni] =
                    __builtin_amdgcn_mfma_scale_f32_16x16x128_f8f6f4(
                        af, bf[ni], acc[mi][ni],
                        0, 0,                      // cbsz=fp8, blgp=fp8
                        0, 0x7F7F7F7F,             // scale A = 2^0
                        0, 0x7F7F7F7F);            // scale B = 2^0
            __builtin_amdgcn_s_setprio(0);
        }
        __syncthreads();   // drains vmcnt+lgkm: next slice resident, WAR safe
    }

    // epilogue: per-row sum of exp over this block's 256 cols -> atomicAdd.
    // C/D (shape-determined, dtype-independent):
    //   col = n0 + wc*64 + ni*16 + ll ; row = m0 + wr*128 + mi*16 + lh*4 + r
    #pragma unroll
    for (int mi = 0; mi < 8; ++mi) {
        #pragma unroll
        for (int r = 0; r < 4; ++r) {
            float s = __expf(acc[mi][0][r]) + __expf(acc[mi][1][r]) +
                      __expf(acc[mi][2][r]) + __expf(acc[mi][3][r]);
            s += __shfl_xor(s, 1, 64);
            s += __shfl_xor(s, 2, 64);
            s += __shfl_xor(s, 4, 64);
            s += __shfl_xor(s, 8, 64);
            if (ll == 0)
                atomicAdd(&rowsum[m0 + wr * 128 + mi * 16 + lh * 4 + r], s);
        }
    }
}

// ---------------- final reduce (single block, fused) -------------------------
__global__ __launch_bounds__(1024) void final_kernel(
    const float* __restrict__ rowsum, const float* __restrict__ pos_sim,
    const float* __restrict__ norm2, float* __restrict__ out)
{
    const int t = threadIdx.x;
    float s1 = 0.f, s2 = 0.f;
    #pragma unroll
    for (int k = 0; k < NR / 1024; ++k) {
        const int i = k * 1024 + t;
        s1 += logf(rowsum[i] + E_CONST) - pos_sim[i];
        s2 += norm2[i];
    }
    #pragma unroll
    for (int m = 1; m < 64; m <<= 1) {
        s1 += __shfl_xor(s1, m, 64);
        s2 += __shfl_xor(s2, m, 64);
    }
    __shared__ float r1[16], r2[16];
    if ((t & 63) == 0) { r1[t >> 6] = s1; r2[t >> 6] = s2; }
    __syncthreads();
    if (t == 0) {
        float a = 0.f, b = 0.f;
        #pragma unroll
        for (int k = 0; k < 16; ++k) { a += r1[k]; b += r2[k]; }
        out[0] = a * (1.0f / NR) + 0.02f * sqrtf(b);
    }
}

extern "C" void kernel_launch(void* const* d_in, const int* in_sizes, int n_in,
                              void* d_out, int out_size, void* d_ws, size_t ws_size,
                              hipStream_t stream) {
    const float* ex = (const float*)d_in[0];
    float* out = (float*)d_out;
    char* ws = (char*)d_ws;
    uchar* Ah      = (uchar*)(ws);                          // 4 MiB
    uchar* Ph      = (uchar*)(ws + 4194304);                // 4 MiB
    float* possim  = (float*)(ws + 8388608);                // 32 KiB
    float* norm2   = (float*)(ws + 8388608 + 32768);        // 32 KiB
    float* rowsum  = (float*)(ws + 8388608 + 65536);        // 32 KiB

    prep_kernel<<<NR, 128, 0, stream>>>(ex, Ah, Ph, possim, norm2, rowsum);
    gemm_kernel<<<dim3(NR / 256, NR / 256), 512, 0, stream>>>(Ah, Ph, rowsum);
    final_kernel<<<1, 1024, 0, stream>>>(rowsum, possim, norm2, out);
}

// Round 9
// 183.896 us; speedup vs baseline: 1.1725x; 1.1725x over previous
//
#include <hip/hip_runtime.h>
#include <hip/hip_bf16.h>

// NPairLoss on MI355X (gfx950).
// loss = mean_i [ log( rowsum_i + e ) - pos_sim_i ] + 0.02*||examples||_F
// rowsum_i = sum_j exp(sim_ij), sim = (A/|A|)·(P/|P|)^T ; diag-replacement -> +e.
//
// R9: fp8-e4m3 scale-MFMA (verified exact R7/R8), but 128x128 tile / 4 waves
// so register pressure PROVABLY fits (acc 64 + bf 32 + af 8 + addr < 128):
// R7/R8 at 256^2 spilled ~600B/thread (WRITE 311MB, FETCH 175MB, MfmaUtil 9%).
// LDS: 2 buffers x (A 16KB + B 16KB) = 64 KB -> 2 blocks/CU.
// Same staging involution: LDS[r][s] = G[r][s^(r&7)], LINEAR LDS dest
// (global_load_lds HW contract), read slot g^(R&7), (R&7)==(ll&7).

#define NR 8192
#define DD 512
#define E_CONST 2.71828182845904523536f

typedef __attribute__((ext_vector_type(4))) float f32x4_t;
typedef __attribute__((ext_vector_type(4))) int   i32x4_t;
typedef __attribute__((ext_vector_type(8))) int   i32x8_t;
typedef unsigned char uchar;
typedef unsigned int  uint;
#define AS1 __attribute__((address_space(1)))
#define AS3 __attribute__((address_space(3)))

// ---------------- prep: normalize rows -> fp8 e4m3, pos_sim, norm2, zero ----
__global__ __launch_bounds__(128) void prep_kernel(
    const float* __restrict__ ex,
    uchar* __restrict__ Ah, uchar* __restrict__ Ph,
    float* __restrict__ pos_sim, float* __restrict__ norm2,
    float* __restrict__ rowsum)
{
    const int i = blockIdx.x;
    const int t = threadIdx.x;            // 0..127, 4 floats each
    const float4 a = ((const float4*)(ex + (size_t)i * 1024))[t];
    const float4 p = ((const float4*)(ex + (size_t)i * 1024 + 512))[t];
    float sa  = a.x*a.x + a.y*a.y + a.z*a.z + a.w*a.w;
    float sp  = p.x*p.x + p.y*p.y + p.z*p.z + p.w*p.w;
    float sap = a.x*p.x + a.y*p.y + a.z*p.z + a.w*p.w;
    #pragma unroll
    for (int m = 1; m < 64; m <<= 1) {
        sa  += __shfl_xor(sa,  m, 64);
        sp  += __shfl_xor(sp,  m, 64);
        sap += __shfl_xor(sap, m, 64);
    }
    __shared__ float red[3][2];
    if ((t & 63) == 0) { red[0][t>>6] = sa; red[1][t>>6] = sp; red[2][t>>6] = sap; }
    __syncthreads();
    sa  = red[0][0] + red[0][1];
    sp  = red[1][0] + red[1][1];
    sap = red[2][0] + red[2][1];
    const float inva = rsqrtf(sa);
    const float invp = rsqrtf(sp);
    uint pa = 0, pp = 0;
    pa = __builtin_amdgcn_cvt_pk_fp8_f32(a.x * inva, a.y * inva, pa, false);
    pa = __builtin_amdgcn_cvt_pk_fp8_f32(a.z * inva, a.w * inva, pa, true);
    pp = __builtin_amdgcn_cvt_pk_fp8_f32(p.x * invp, p.y * invp, pp, false);
    pp = __builtin_amdgcn_cvt_pk_fp8_f32(p.z * invp, p.w * invp, pp, true);
    ((uint*)Ah)[i * 128 + t] = pa;
    ((uint*)Ph)[i * 128 + t] = pp;
    if (t == 0) {
        pos_sim[i] = sap * inva * invp;
        norm2[i]   = sa + sp;
        rowsum[i]  = 0.0f;
    }
}

// ---------------- GEMM 128^2 fp8, 4 slices of K=128, 2-phase dbuf -----------
__global__ __launch_bounds__(256, 2) void gemm_kernel(
    const uchar* __restrict__ Ah, const uchar* __restrict__ Ph,
    float* __restrict__ rowsum)
{
    // ls: 2 buffers x (A: 128x128B + B: 128x128B) = 2 x 32 KiB = 64 KiB
    __shared__ uchar ls[65536];
    const int t  = threadIdx.x;           // 0..255
    const int w  = t >> 6;                // wave 0..3
    const int l  = t & 63;
    const int wr = w >> 1, wc = w & 1;    // 2M x 2N wave grid
    const int ll = l & 15, lh = l >> 4;
    const int m0 = blockIdx.y * 128;
    const int n0 = blockIdx.x * 128;

    f32x4_t acc[4][4];
    #pragma unroll
    for (int i = 0; i < 4; i++)
        #pragma unroll
        for (int j = 0; j < 4; j++)
            acc[i][j] = (f32x4_t){0.f, 0.f, 0.f, 0.f};

    // staging: chunk = one matrix x one slice = 128 rows x 128 B = 16 KiB.
    // wave w, instr j: rows w*32+j*8..+8 -> 1 KiB LINEAR LDS (lane l at +l*16).
    // lane l -> row r = w*32+j*8+(l>>3), slot l&7.
    // Source fetches slot (l&7)^(r&7) => LDS[r][s] = G[r][s^(r&7)] involution.
    auto stage = [&](const uchar* src, int s, int matOff, int rowBase) {
        const int buf = s & 1;
        #pragma unroll
        for (int j = 0; j < 4; ++j) {
            const int r  = w * 32 + j * 8 + (l >> 3);
            const int gs = (l & 7) ^ (r & 7);
            const uchar* g = src + (size_t)(rowBase + r) * DD + s * 128 + gs * 16;
            __builtin_amdgcn_global_load_lds(
                (const AS1 void*)g,
                (AS3 void*)(&ls[buf * 32768 + matOff + w * 4096 + j * 1024 + l * 16]),
                16, 0, 0);
        }
    };

    // fragment read: row R, lane wants global 16B-slots g=lh*2, lh*2+1 at
    // LDS slots g ^ (R&7), with (R&7) == (ll&7) (row bases 16-aligned).
    auto rdfrag = [&](int base, int R) -> i32x8_t {
        const int rb = base + R * 128;
        i32x4_t lo = *(const i32x4_t*)&ls[rb + (((lh * 2)    ) ^ (ll & 7)) * 16];
        i32x4_t hi = *(const i32x4_t*)&ls[rb + (((lh * 2) + 1) ^ (ll & 7)) * 16];
        return __builtin_shufflevector(lo, hi, 0, 1, 2, 3, 4, 5, 6, 7);
    };

    // prologue: stage slice 0, drain, barrier.
    stage(Ah, 0, 0,     m0);
    stage(Ph, 0, 16384, n0);
    __syncthreads();

    #pragma unroll
    for (int s = 0; s < 4; ++s) {
        // issue next slice's stages EARLY (latency hides under compute)
        if (s < 3) {
            stage(Ah, s + 1, 0,     m0);
            stage(Ph, s + 1, 16384, n0);
        }
        const int aB = (s & 1) * 32768;
        const int bB = aB + 16384;

        i32x8_t bf[4];
        #pragma unroll
        for (int ni = 0; ni < 4; ++ni)
            bf[ni] = rdfrag(bB, wc * 64 + ni * 16 + ll);

        #pragma unroll
        for (int mi = 0; mi < 4; ++mi) {
            i32x8_t af = rdfrag(aB, wr * 64 + mi * 16 + ll);
            __builtin_amdgcn_s_setprio(1);
            #pragma unroll
            for (int ni = 0; ni < 4; ++ni)
                acc[mi][ni] =
                    __builtin_amdgcn_mfma_scale_f32_16x16x128_f8f6f4(
                        af, bf[ni], acc[mi][ni],
                        0, 0,                      // cbsz=fp8, blgp=fp8
                        0, 0x7F7F7F7F,             // scale A = 2^0
                        0, 0x7F7F7F7F);            // scale B = 2^0
            __builtin_amdgcn_s_setprio(0);
        }
        __syncthreads();   // drains vmcnt+lgkm: next slice resident, WAR safe
    }

    // epilogue: per-row sum of exp over this block's 128 cols -> atomicAdd.
    // C/D (shape-determined): col = n0 + wc*64 + ni*16 + ll ;
    //                         row = m0 + wr*64 + mi*16 + lh*4 + r
    #pragma unroll
    for (int mi = 0; mi < 4; ++mi) {
        #pragma unroll
        for (int r = 0; r < 4; ++r) {
            float s = __expf(acc[mi][0][r]) + __expf(acc[mi][1][r]) +
                      __expf(acc[mi][2][r]) + __expf(acc[mi][3][r]);
            s += __shfl_xor(s, 1, 64);
            s += __shfl_xor(s, 2, 64);
            s += __shfl_xor(s, 4, 64);
            s += __shfl_xor(s, 8, 64);
            if (ll == 0)
                atomicAdd(&rowsum[m0 + wr * 64 + mi * 16 + lh * 4 + r], s);
        }
    }
}

// ---------------- final reduce (single block, fused) -------------------------
__global__ __launch_bounds__(1024) void final_kernel(
    const float* __restrict__ rowsum, const float* __restrict__ pos_sim,
    const float* __restrict__ norm2, float* __restrict__ out)
{
    const int t = threadIdx.x;
    float s1 = 0.f, s2 = 0.f;
    #pragma unroll
    for (int k = 0; k < NR / 1024; ++k) {
        const int i = k * 1024 + t;
        s1 += logf(rowsum[i] + E_CONST) - pos_sim[i];
        s2 += norm2[i];
    }
    #pragma unroll
    for (int m = 1; m < 64; m <<= 1) {
        s1 += __shfl_xor(s1, m, 64);
        s2 += __shfl_xor(s2, m, 64);
    }
    __shared__ float r1[16], r2[16];
    if ((t & 63) == 0) { r1[t >> 6] = s1; r2[t >> 6] = s2; }
    __syncthreads();
    if (t == 0) {
        float a = 0.f, b = 0.f;
        #pragma unroll
        for (int k = 0; k < 16; ++k) { a += r1[k]; b += r2[k]; }
        out[0] = a * (1.0f / NR) + 0.02f * sqrtf(b);
    }
}

extern "C" void kernel_launch(void* const* d_in, const int* in_sizes, int n_in,
                              void* d_out, int out_size, void* d_ws, size_t ws_size,
                              hipStream_t stream) {
    const float* ex = (const float*)d_in[0];
    float* out = (float*)d_out;
    char* ws = (char*)d_ws;
    uchar* Ah      = (uchar*)(ws);                          // 4 MiB
    uchar* Ph      = (uchar*)(ws + 4194304);                // 4 MiB
    float* possim  = (float*)(ws + 8388608);                // 32 KiB
    float* norm2   = (float*)(ws + 8388608 + 32768);        // 32 KiB
    float* rowsum  = (float*)(ws + 8388608 + 65536);        // 32 KiB

    prep_kernel<<<NR, 128, 0, stream>>>(ex, Ah, Ph, possim, norm2, rowsum);
    gemm_kernel<<<dim3(NR / 128, NR / 128), 256, 0, stream>>>(Ah, Ph, rowsum);
    final_kernel<<<1, 1024, 0, stream>>>(rowsum, possim, norm2, out);
}